// Round 5
// baseline (88.382 us; speedup 1.0000x reference)
//
#include <hip/hip_runtime.h>

#define GRIDN 256
#define NVOX (GRIDN * GRIDN * GRIDN)   // 16,777,216 voxels, 64 MiB fp32

// ---------------------------------------------------------------------------
// Fast fill: float4 grid-stride zero.
// ---------------------------------------------------------------------------
__global__ __launch_bounds__(256) void k_zero4(float4* __restrict__ p, int n4) {
    int stride = gridDim.x * blockDim.x;
    float4 z = make_float4(0.f, 0.f, 0.f, 0.f);
    for (int i = blockIdx.x * blockDim.x + threadIdx.x; i < n4; i += stride)
        p[i] = z;
}

// ---------------------------------------------------------------------------
// Scatter: vol[d][h][w] += feats[i].
// ---------------------------------------------------------------------------
__global__ void k_scatter(const float* __restrict__ feats,
                          const int* __restrict__ coords,
                          float* __restrict__ vol, int n) {
    int i = blockIdx.x * blockDim.x + threadIdx.x;
    if (i >= n) return;
    int d = coords[3 * i + 0];
    int h = coords[3 * i + 1];
    int w = coords[3 * i + 2];
    atomicAdd(&vol[(d * GRIDN + h) * GRIDN + w], feats[i]);
}

// ---------------------------------------------------------------------------
// Fully fused 5x5x5 box conv, v2.
// Block = 256 threads, tile 64(x) x 16(y), streams ZS=16 output slices
// (20 input slices incl. halo). Grid = 4*16*16 = 1024 blocks (4/CU).
// Per slice (2 barriers):
//   stage R[20][72] (float4, zero-padded)          -> BAR_A
//   x-pass (vectorized): Xp4 = 3x ds_read_b128     -> BAR_B
//   y-pass: 5 aligned float4 rows of Xp -> v
// Hazards: ypass(k) reads Xp, xpass(k+1) writes Xp -- separated by BAR_A(k+1);
// xpass(k) reads R, stage(k+1) writes R -- separated by BAR_B(k).
// 5-deep float4 register ring (static shift) for z; one float4 store/thread.
// ---------------------------------------------------------------------------
#define TXF 64
#define TYF 16
#define ZS  16
__global__ __launch_bounds__(256) void k_fused(const float* __restrict__ in,
                                               float* __restrict__ out) {
    __shared__ float R[TYF + 4][72];   // x: x0-4 .. x0+67 (f4-aligned halo)
    __shared__ float Xp[TYF + 4][68];  // cols 0..63 used; 68 rotates banks/row

    const int tid = threadIdx.x;
    const int x0  = blockIdx.x * TXF;
    const int y0  = blockIdx.y * TYF;
    const int z0  = blockIdx.z * ZS;
    const int xq  = (tid & 15) * 4;    // thread's 4 consecutive x
    const int yy  = tid >> 4;          // thread's y row, 0..15

    float4 a0 = {0,0,0,0}, a1 = {0,0,0,0}, a2 = {0,0,0,0},
           a3 = {0,0,0,0}, a4 = {0,0,0,0};

    for (int zi = z0 - 2; zi < z0 + ZS + 2; ++zi) {
        float4 v = {0,0,0,0};
        if ((unsigned)zi < (unsigned)GRIDN) {
            const float4* slice4 = (const float4*)(in + (size_t)zi * (GRIDN * GRIDN));
            // stage 20 rows x 18 float4, zero-padded outside the volume
            for (int idx = tid; idx < 20 * 18; idx += 256) {
                int row = idx / 18;
                int c4  = idx - row * 18;
                int gy  = y0 + row - 2;
                int gx4 = (x0 >> 2) - 1 + c4;
                float4 val = {0,0,0,0};
                if ((unsigned)gy < (unsigned)GRIDN && (unsigned)gx4 < (unsigned)(GRIDN / 4))
                    val = slice4[gy * (GRIDN / 4) + gx4];
                *(float4*)&R[row][c4 * 4] = val;
            }
            __syncthreads();                       // BAR_A
            // x-pass, vectorized: 20 rows x 16 float4 outputs
            for (int idx = tid; idx < 20 * 16; idx += 256) {
                int row = idx >> 4;
                int c   = idx & 15;
                float4 v0 = *(const float4*)&R[row][c * 4];
                float4 v1 = *(const float4*)&R[row][c * 4 + 4];
                float4 v2 = *(const float4*)&R[row][c * 4 + 8];
                float s123 = v1.x + v1.y + v1.z;
                float4 o;
                o.x = v0.z + v0.w + s123;
                o.y = v0.w + s123 + v1.w;
                o.z = s123 + v1.w + v2.x;
                o.w = v1.y + v1.z + v1.w + v2.x + v2.y;
                *(float4*)&Xp[row][c * 4] = o;
            }
            __syncthreads();                       // BAR_B
            // y-pass: 5 aligned float4 rows
            float4 r0 = *(const float4*)&Xp[yy + 0][xq];
            float4 r1 = *(const float4*)&Xp[yy + 1][xq];
            float4 r2 = *(const float4*)&Xp[yy + 2][xq];
            float4 r3 = *(const float4*)&Xp[yy + 3][xq];
            float4 r4 = *(const float4*)&Xp[yy + 4][xq];
            v.x = r0.x + r1.x + r2.x + r3.x + r4.x;
            v.y = r0.y + r1.y + r2.y + r3.y + r4.y;
            v.z = r0.z + r1.z + r2.z + r3.z + r4.z;
            v.w = r0.w + r1.w + r2.w + r3.w + r4.w;
        }
        // shift z-ring (static indices only)
        a0 = a1; a1 = a2; a2 = a3; a3 = a4; a4 = v;
        int zo = zi - 2;
        if (zo >= z0) {
            float4 s;
            s.x = a0.x + a1.x + a2.x + a3.x + a4.x;
            s.y = a0.y + a1.y + a2.y + a3.y + a4.y;
            s.z = a0.z + a1.z + a2.z + a3.z + a4.z;
            s.w = a0.w + a1.w + a2.w + a3.w + a4.w;
            float4* op = (float4*)(out + (size_t)zo * (GRIDN * GRIDN)
                                       + (size_t)(y0 + yy) * GRIDN + x0 + xq);
            *op = s;
        }
    }
}

// ---------------------------------------------------------------------------
// Fallback if ws is too small: direct 125-way atomic expansion.
// ---------------------------------------------------------------------------
__global__ void k_scatter125(const float* __restrict__ feats,
                             const int* __restrict__ coords,
                             float* __restrict__ out, int n) {
    int i = blockIdx.x * blockDim.x + threadIdx.x;
    if (i >= n) return;
    int d = coords[3 * i + 0];
    int h = coords[3 * i + 1];
    int w = coords[3 * i + 2];
    float f = feats[i];
    int d0 = max(d - 2, 0), d1 = min(d + 2, GRIDN - 1);
    int h0 = max(h - 2, 0), h1 = min(h + 2, GRIDN - 1);
    int w0 = max(w - 2, 0), w1 = min(w + 2, GRIDN - 1);
    for (int dd = d0; dd <= d1; ++dd)
        for (int hh = h0; hh <= h1; ++hh)
            for (int ww = w0; ww <= w1; ++ww)
                atomicAdd(&out[(dd * GRIDN + hh) * GRIDN + ww], f);
}

extern "C" void kernel_launch(void* const* d_in, const int* in_sizes, int n_in,
                              void* d_out, int out_size, void* d_ws, size_t ws_size,
                              hipStream_t stream) {
    const float* feats  = (const float*)d_in[0];
    const int*   coords = (const int*)d_in[1];
    float*       out    = (float*)d_out;
    int n = in_sizes[0];

    const size_t vol_bytes = (size_t)NVOX * sizeof(float);

    if (ws_size >= vol_bytes) {
        float* ws = (float*)d_ws;
        // 1. Zero ws, scatter active voxels into it.
        k_zero4<<<2048, 256, 0, stream>>>((float4*)ws, NVOX / 4);
        k_scatter<<<(n + 255) / 256, 256, 0, stream>>>(feats, coords, ws, n);
        // 2. Single fused x+y+z box pass: ws -> out.
        dim3 grid(GRIDN / TXF, GRIDN / TYF, GRIDN / ZS);
        k_fused<<<grid, 256, 0, stream>>>(ws, out);
    } else {
        k_zero4<<<2048, 256, 0, stream>>>((float4*)out, NVOX / 4);
        k_scatter125<<<(n + 255) / 256, 256, 0, stream>>>(feats, coords, out, n);
    }
}

// Round 7
// 86.950 us; speedup vs baseline: 1.0165x; 1.0165x over previous
//
#include <hip/hip_runtime.h>

#define GRIDN 256
#define NVOX (GRIDN * GRIDN * GRIDN)   // 16,777,216 voxels, 64 MiB fp32

typedef float floatx4 __attribute__((ext_vector_type(4)));

// ---------------------------------------------------------------------------
// Prep: pack (d,h,w) -> linear voxel index. Independent of everything else;
// placed FIRST in the graph to absorb any replay-boundary flush stall.
// ---------------------------------------------------------------------------
__global__ __launch_bounds__(256) void k_prep(const int* __restrict__ coords,
                                              int* __restrict__ lin, int n) {
    int i = blockIdx.x * blockDim.x + threadIdx.x;
    if (i >= n) return;
    int d = coords[3 * i + 0];
    int h = coords[3 * i + 1];
    int w = coords[3 * i + 2];
    lin[i] = (d * GRIDN + h) * GRIDN + w;
}

// ---------------------------------------------------------------------------
// Zero-fill with nontemporal (streaming) stores: probe whether the measured
// ~1.5 TB/s 64MB-fill pathology is a cache-allocate effect.
// ---------------------------------------------------------------------------
__global__ __launch_bounds__(256) void k_zero4(floatx4* __restrict__ p, int n4) {
    int stride = gridDim.x * blockDim.x;
    floatx4 z = {0.f, 0.f, 0.f, 0.f};
    for (int i = blockIdx.x * blockDim.x + threadIdx.x; i < n4; i += stride)
        __builtin_nontemporal_store(z, &p[i]);
}

// ---------------------------------------------------------------------------
// Scatter using precomputed linear indices.
// ---------------------------------------------------------------------------
__global__ __launch_bounds__(256) void k_scatter(const float* __restrict__ feats,
                                                 const int* __restrict__ lin,
                                                 float* __restrict__ vol, int n) {
    int i = blockIdx.x * blockDim.x + threadIdx.x;
    if (i >= n) return;
    atomicAdd(&vol[lin[i]], feats[i]);
}

// ---------------------------------------------------------------------------
// Fully fused 5x5x5 box conv, v3: register-prefetch software pipeline.
// Block = 256 thr, tile 64(x) x 16(y) x 16(z out). Grid = 1024 blocks,
// XCD-chunked swizzle (128 consecutive blocks = 2 z-planes per XCD).
// Per slice: {commit staged regs -> LDS R; issue prefetch of slice k+1}
//   BAR_A; vector x-pass R->Xp; BAR_B; y-pass + z-ring + store.
// Prefetch loads (1-2 float4/thread) are in flight across BAR_A+xpass+BAR_B+
// ypass -> stage latency hidden. Xp stride 64 (round-4 layout, 0 conflicts).
// ---------------------------------------------------------------------------
#define TXF 64
#define TYF 16
#define ZS  16
__global__ __launch_bounds__(256) void k_fused(const float4* __restrict__ in4,
                                               float* __restrict__ out) {
    __shared__ float R[TYF + 4][72];   // global x0-4 .. x0+67
    __shared__ float Xp[TYF + 4][64];  // global x0 .. x0+63

    const int tid = threadIdx.x;

    // XCD-chunked swizzle: 1024 blocks, 8 XCDs, 128-block chunks.
    int wg  = blockIdx.x;
    int swz = (wg & 7) * 128 + (wg >> 3);
    const int x0 = (swz & 3) * TXF;
    const int y0 = ((swz >> 2) & 15) * TYF;
    const int z0 = (swz >> 6) * ZS;

    const int xq = (tid & 15) * 4;     // thread's 4 consecutive x
    const int yy = tid >> 4;           // thread's y row, 0..15

    // Stage slots: 20 rows x 18 float4 = 360 items; slot0 = tid, slot1 = tid+256.
    const int i1   = tid + 256;
    const int row0 = tid / 18, c40 = tid - row0 * 18;
    const int row1 = i1 / 18,  c41 = i1 - row1 * 18;
    const int gy0 = y0 + row0 - 2, gx0 = (x0 >> 2) - 1 + c40;
    const int gy1 = y0 + row1 - 2, gx1 = (x0 >> 2) - 1 + c41;
    const bool ok0 = ((unsigned)gy0 < (unsigned)GRIDN) && ((unsigned)gx0 < 64u);
    const bool ok1 = (i1 < 360) && ((unsigned)gy1 < (unsigned)GRIDN) && ((unsigned)gx1 < 64u);
    const int off0 = gy0 * 64 + gx0;   // within-slice float4 offset
    const int off1 = gy1 * 64 + gx1;

    float4 r0 = {0, 0, 0, 0}, r1 = {0, 0, 0, 0};
    // Prologue: prefetch first slice (zi = z0-2).
    if ((unsigned)(z0 - 2) < (unsigned)GRIDN) {
        const float4* s = in4 + (size_t)(z0 - 2) * (GRIDN * GRIDN / 4);
        if (ok0) r0 = s[off0];
        if (ok1) r1 = s[off1];
    }

    float4 a0 = {0,0,0,0}, a1 = {0,0,0,0}, a2 = {0,0,0,0},
           a3 = {0,0,0,0}, a4 = {0,0,0,0};

    for (int zi = z0 - 2; zi < z0 + ZS + 2; ++zi) {
        // Commit staged regs (slice zi) to LDS.
        *(float4*)&R[row0][c40 * 4] = r0;
        if (i1 < 360) *(float4*)&R[row1][c41 * 4] = r1;
        // Issue prefetch for slice zi+1 (in flight across the whole compute).
        {
            int zn = zi + 1;
            r0 = make_float4(0.f, 0.f, 0.f, 0.f);
            r1 = make_float4(0.f, 0.f, 0.f, 0.f);
            if (zn < z0 + ZS + 2 && (unsigned)zn < (unsigned)GRIDN) {
                const float4* s = in4 + (size_t)zn * (GRIDN * GRIDN / 4);
                if (ok0) r0 = s[off0];
                if (ok1) r1 = s[off1];
            }
        }
        __syncthreads();                       // BAR_A: R complete
        // x-pass, vectorized: 20 rows x 16 float4 outputs.
        for (int idx = tid; idx < 20 * 16; idx += 256) {
            int row = idx >> 4;
            int c   = idx & 15;
            float4 v0 = *(const float4*)&R[row][c * 4];
            float4 v1 = *(const float4*)&R[row][c * 4 + 4];
            float4 v2 = *(const float4*)&R[row][c * 4 + 8];
            float s123 = v1.x + v1.y + v1.z;
            float4 o;
            o.x = v0.z + v0.w + s123;
            o.y = v0.w + s123 + v1.w;
            o.z = s123 + v1.w + v2.x;
            o.w = v1.y + v1.z + v1.w + v2.x + v2.y;
            *(float4*)&Xp[row][c * 4] = o;
        }
        __syncthreads();                       // BAR_B: Xp complete
        // y-pass: 5 aligned float4 rows.
        float4 q0 = *(const float4*)&Xp[yy + 0][xq];
        float4 q1 = *(const float4*)&Xp[yy + 1][xq];
        float4 q2 = *(const float4*)&Xp[yy + 2][xq];
        float4 q3 = *(const float4*)&Xp[yy + 3][xq];
        float4 q4 = *(const float4*)&Xp[yy + 4][xq];
        float4 v;
        v.x = q0.x + q1.x + q2.x + q3.x + q4.x;
        v.y = q0.y + q1.y + q2.y + q3.y + q4.y;
        v.z = q0.z + q1.z + q2.z + q3.z + q4.z;
        v.w = q0.w + q1.w + q2.w + q3.w + q4.w;
        // z-ring shift (static indices only).
        a0 = a1; a1 = a2; a2 = a3; a3 = a4; a4 = v;
        int zo = zi - 2;
        if (zo >= z0) {
            float4 s;
            s.x = a0.x + a1.x + a2.x + a3.x + a4.x;
            s.y = a0.y + a1.y + a2.y + a3.y + a4.y;
            s.z = a0.z + a1.z + a2.z + a3.z + a4.z;
            s.w = a0.w + a1.w + a2.w + a3.w + a4.w;
            float4* op = (float4*)(out + (size_t)zo * (GRIDN * GRIDN)
                                       + (size_t)(y0 + yy) * GRIDN + x0 + xq);
            *op = s;
        }
    }
}

// ---------------------------------------------------------------------------
// Fallback if ws is too small: direct 125-way atomic expansion.
// ---------------------------------------------------------------------------
__global__ void k_scatter125(const float* __restrict__ feats,
                             const int* __restrict__ coords,
                             float* __restrict__ out, int n) {
    int i = blockIdx.x * blockDim.x + threadIdx.x;
    if (i >= n) return;
    int d = coords[3 * i + 0];
    int h = coords[3 * i + 1];
    int w = coords[3 * i + 2];
    float f = feats[i];
    int d0 = max(d - 2, 0), d1 = min(d + 2, GRIDN - 1);
    int h0 = max(h - 2, 0), h1 = min(h + 2, GRIDN - 1);
    int w0 = max(w - 2, 0), w1 = min(w + 2, GRIDN - 1);
    for (int dd = d0; dd <= d1; ++dd)
        for (int hh = h0; hh <= h1; ++hh)
            for (int ww = w0; ww <= w1; ++ww)
                atomicAdd(&out[(dd * GRIDN + hh) * GRIDN + ww], f);
}

extern "C" void kernel_launch(void* const* d_in, const int* in_sizes, int n_in,
                              void* d_out, int out_size, void* d_ws, size_t ws_size,
                              hipStream_t stream) {
    const float* feats  = (const float*)d_in[0];
    const int*   coords = (const int*)d_in[1];
    float*       out    = (float*)d_out;
    int n = in_sizes[0];

    const size_t vol_bytes = (size_t)NVOX * sizeof(float);
    const size_t lin_bytes = (size_t)n * sizeof(int);

    if (ws_size >= vol_bytes + lin_bytes) {
        float* ws  = (float*)d_ws;
        int*   lin = (int*)((char*)d_ws + vol_bytes);
        // 1. prep (first in graph; independent), zero ws, scatter.
        k_prep<<<(n + 255) / 256, 256, 0, stream>>>(coords, lin, n);
        k_zero4<<<4096, 256, 0, stream>>>((floatx4*)ws, NVOX / 4);
        k_scatter<<<(n + 255) / 256, 256, 0, stream>>>(feats, lin, ws, n);
        // 2. Single fused x+y+z box pass: ws -> out.
        k_fused<<<1024, 256, 0, stream>>>((const float4*)ws, out);
    } else {
        k_zero4<<<4096, 256, 0, stream>>>((floatx4*)out, NVOX / 4);
        k_scatter125<<<(n + 255) / 256, 256, 0, stream>>>(feats, coords, out, n);
    }
}